// Round 1
// baseline (4221.804 us; speedup 1.0000x reference)
//
#include <hip/hip_runtime.h>

#define B_   4
#define L_   8192
#define D_   2048
#define H_   32
#define HD_  64
#define WIN_ 1024
#define U_   512      // tokens per (window, parity) slice
#define PAD_ 68       // 64 + 4 pad: breaks 256B-stride bank aliasing, keeps 16B align

// K1: one block per (b, window, parity, head). LDS holds the 512-token parity
// slice of this head (fp32). Each thread owns one query token: computes all 6
// dilation rates' softmax-attention outputs (each rate normalized) summed into
// acc[64], plus the summed softmax denominator den_tok. Writes unscaled acc to
// out and den_tok to the den scratch buffer.
__global__ __launch_bounds__(512, 2)
void ddattn_k1(const float* __restrict__ x, float* __restrict__ out,
               float* __restrict__ den) {
    const int bid = blockIdx.x;
    const int h   = bid & 31;
    const int p   = (bid >> 5) & 1;
    const int win = (bid >> 6) & 7;
    const int b   = bid >> 9;

    __shared__ float Xs[U_ * PAD_];

    const int t0 = win * WIN_;
    const float* xb = x + ((size_t)b * L_ + (size_t)(t0 + p)) * D_ + h * HD_;

    // stage: 512 rows x 64 floats (each row = one parity-class token's head slice)
    for (int idx = threadIdx.x; idx < U_ * 16; idx += 512) {
        const int row = idx >> 4;
        const int c   = idx & 15;
        const float4 v4 = *(const float4*)(xb + (size_t)row * (2 * D_) + c * 4);
        *(float4*)(&Xs[row * PAD_ + c * 4]) = v4;
    }
    __syncthreads();

    const int u = threadIdx.x;   // query slot 0..511
    const int v = 2 * u + p;     // offset within the 1024-token window

    // query vector in registers
    float4 Q[16];
#pragma unroll
    for (int c = 0; c < 16; c++) Q[c] = *(const float4*)(&Xs[u * PAD_ + c * 4]);

    // rate 0 (seg=1): probs==1, out = x, den = exp(|x|^2/8)
    float q0 = 0.f, q1 = 0.f, q2 = 0.f, q3 = 0.f;
#pragma unroll
    for (int c = 0; c < 16; c++) {
        q0 = fmaf(Q[c].x, Q[c].x, q0);
        q1 = fmaf(Q[c].y, Q[c].y, q1);
        q2 = fmaf(Q[c].z, Q[c].z, q2);
        q3 = fmaf(Q[c].w, Q[c].w, q3);
    }
    float den_tok = __expf(((q0 + q1) + (q2 + q3)) * 0.125f);

    float4 acc[16];
#pragma unroll
    for (int c = 0; c < 16; c++) acc[c] = Q[c];

    // rates 1..5: group of token v at rate i = { (v/4^i)*4^i + k*2^i + (v mod 2^i) }
#pragma unroll
    for (int i = 1; i <= 5; i++) {
        const int s  = 1 << i;
        const int vb = ((v >> (2 * i)) << (2 * i)) | (v & (s - 1));
        float4 E[16];
#pragma unroll
        for (int c = 0; c < 16; c++) E[c] = make_float4(0.f, 0.f, 0.f, 0.f);
        float Dr = 0.f;
        for (int k = 0; k < s; k++) {
            const int uk = ((vb + (k << i)) - p) >> 1;
            const float4* Krow = (const float4*)(&Xs[uk * PAD_]);
            float d0 = 0.f, d1 = 0.f, d2 = 0.f, d3 = 0.f;
#pragma unroll
            for (int c = 0; c < 16; c++) {
                const float4 kv = Krow[c];
                d0 = fmaf(Q[c].x, kv.x, d0);
                d1 = fmaf(Q[c].y, kv.y, d1);
                d2 = fmaf(Q[c].z, kv.z, d2);
                d3 = fmaf(Q[c].w, kv.w, d3);
            }
            // scores <= ~16 here, exp safely in fp32 range: no max-shift needed
            const float e = __expf(((d0 + d1) + (d2 + d3)) * 0.125f);
            Dr += e;
#pragma unroll
            for (int c = 0; c < 16; c++) {
                const float4 kv = Krow[c];
                E[c].x = fmaf(e, kv.x, E[c].x);
                E[c].y = fmaf(e, kv.y, E[c].y);
                E[c].z = fmaf(e, kv.z, E[c].z);
                E[c].w = fmaf(e, kv.w, E[c].w);
            }
        }
        den_tok += Dr;
        const float r = 1.0f / Dr;
#pragma unroll
        for (int c = 0; c < 16; c++) {
            acc[c].x = fmaf(E[c].x, r, acc[c].x);
            acc[c].y = fmaf(E[c].y, r, acc[c].y);
            acc[c].z = fmaf(E[c].z, r, acc[c].z);
            acc[c].w = fmaf(E[c].w, r, acc[c].w);
        }
    }

    const int t = t0 + v;
    float* op = out + ((size_t)b * L_ + t) * D_ + h * HD_;
#pragma unroll
    for (int c = 0; c < 16; c++) *(float4*)(op + c * 4) = acc[c];
    den[((size_t)b * L_ + t) * H_ + h] = den_tok;
}

// K2: per token, w = softmax over heads of den (with max-shift: den can be ~1e7),
// scale the 2048-wide output row in place.
__global__ __launch_bounds__(256)
void ddattn_k2(float* __restrict__ out, const float* __restrict__ den) {
    const int tok = blockIdx.x;  // 0 .. B*L-1
    __shared__ float sden[H_];
    if (threadIdx.x < H_) sden[threadIdx.x] = den[(size_t)tok * H_ + threadIdx.x];
    __syncthreads();

    float mx = -3.4e38f;
#pragma unroll
    for (int hh = 0; hh < H_; hh++) mx = fmaxf(mx, sden[hh]);
    float sum = 0.f;
#pragma unroll
    for (int hh = 0; hh < H_; hh++) sum += __expf(sden[hh] - mx);
    const float inv = 1.0f / sum;

    float4* o4 = (float4*)(out + (size_t)tok * D_);
#pragma unroll
    for (int it = 0; it < 2; it++) {
        const int idx = it * 256 + threadIdx.x;  // 0..511 float4 chunks
        const int hh  = idx >> 4;                // 16 float4 per head
        const float w = __expf(sden[hh] - mx) * inv;
        float4 vv = o4[idx];
        vv.x *= w; vv.y *= w; vv.z *= w; vv.w *= w;
        o4[idx] = vv;
    }
}

extern "C" void kernel_launch(void* const* d_in, const int* in_sizes, int n_in,
                              void* d_out, int out_size, void* d_ws, size_t ws_size,
                              hipStream_t stream) {
    const float* x = (const float*)d_in[0];
    float* out = (float*)d_out;
    float* den = (float*)d_ws;  // B*L*H fp32 = 4 MB scratch

    ddattn_k1<<<dim3(B_ * (L_ / WIN_) * 2 * H_), dim3(512), 0, stream>>>(x, out, den);
    ddattn_k2<<<dim3(B_ * L_), dim3(256), 0, stream>>>(out, den);
}

// Round 2
// 1652.604 us; speedup vs baseline: 2.5546x; 2.5546x over previous
//
#include <hip/hip_runtime.h>

#define B_   4
#define L_   8192
#define D_   2048
#define H_   32
#define WIN_ 1024
#define U_   512      // tokens per (window, parity) slice
#define PAD_ 68       // 64 + 4 pad

// quarter-dot over 16 dims (4 float4)
__device__ __forceinline__ float dot16(const float4 (&Q)[4], const float4& R0,
                                       const float4& R1, const float4& R2, const float4& R3) {
    float a0 = 0.f, a1 = 0.f, a2 = 0.f, a3 = 0.f;
    a0 = fmaf(Q[0].x, R0.x, a0); a1 = fmaf(Q[0].y, R0.y, a1);
    a2 = fmaf(Q[0].z, R0.z, a2); a3 = fmaf(Q[0].w, R0.w, a3);
    a0 = fmaf(Q[1].x, R1.x, a0); a1 = fmaf(Q[1].y, R1.y, a1);
    a2 = fmaf(Q[1].z, R1.z, a2); a3 = fmaf(Q[1].w, R1.w, a3);
    a0 = fmaf(Q[2].x, R2.x, a0); a1 = fmaf(Q[2].y, R2.y, a1);
    a2 = fmaf(Q[2].z, R2.z, a2); a3 = fmaf(Q[2].w, R2.w, a3);
    a0 = fmaf(Q[3].x, R3.x, a0); a1 = fmaf(Q[3].y, R3.y, a1);
    a2 = fmaf(Q[3].z, R3.z, a2); a3 = fmaf(Q[3].w, R3.w, a3);
    return (a0 + a1) + (a2 + a3);
}

// complete a head-dim dot across the 4 quarter-lanes (lanes 4j..4j+3)
__device__ __forceinline__ float qreduce(float d) {
    d += __shfl_xor(d, 1);
    d += __shfl_xor(d, 2);
    return d;
}

// K1: one block per (b, win, parity, head, query-half). 512 threads =
// 128 query-PAIRS (u, u+16) x 4 head-dim quarters. The pair shares identical
// rate-4 and rate-5 groups, so those key rows are read from LDS once for both
// queries. Per-thread state ~64 VGPRs -> no spills.
__global__ __launch_bounds__(512, 2)
void ddattn_k1(const float* __restrict__ x, float* __restrict__ out,
               float* __restrict__ den) {
    const int bid = blockIdx.x;
    const int qhf = bid & 1;
    const int h   = (bid >> 1) & 31;
    const int p   = (bid >> 6) & 1;
    const int win = (bid >> 7) & 7;
    const int b   = bid >> 10;

    __shared__ float Xs[U_ * PAD_];
    const int t0 = win * WIN_;
    const float* xb = x + ((size_t)b * L_ + (size_t)(t0 + p)) * D_ + h * 64;

    for (int idx = threadIdx.x; idx < U_ * 16; idx += 512) {
        const int row = idx >> 4, c = idx & 15;
        *(float4*)(&Xs[row * PAD_ + c * 4]) =
            *(const float4*)(xb + (size_t)row * (2 * D_) + c * 4);
    }
    __syncthreads();

    const int qt = threadIdx.x & 3;        // head-dim quarter 0..3
    const int j  = threadIdx.x >> 2;       // pair slot 0..127
    const int u0 = (j & 15) + 32 * (j >> 4) + 256 * qhf;
    const int u1 = u0 + 16;
    const int qoff = qt * 16;

    float4 Q0[4], Q1[4];
#pragma unroll
    for (int c = 0; c < 4; c++) Q0[c] = *(const float4*)(&Xs[u0 * PAD_ + qoff + c * 4]);
#pragma unroll
    for (int c = 0; c < 4; c++) Q1[c] = *(const float4*)(&Xs[u1 * PAD_ + qoff + c * 4]);

    // rate 0: probs == 1 -> out += x ; den = exp(|x|^2/8)
    float4 acc0[4], acc1[4];
#pragma unroll
    for (int c = 0; c < 4; c++) { acc0[c] = Q0[c]; acc1[c] = Q1[c]; }
    float den0 = __expf(qreduce(dot16(Q0, Q0[0], Q0[1], Q0[2], Q0[3])) * 0.125f);
    float den1 = __expf(qreduce(dot16(Q1, Q1[0], Q1[1], Q1[2], Q1[3])) * 0.125f);

    // rates 1..3: groups differ between u0 and u1 -> per query
    auto rates123 = [&](const float4 (&Q)[4], const int u, float4 (&acc)[4], float& dn) {
#pragma unroll
        for (int i = 1; i <= 3; i++) {
            const int step = 1 << (i - 1);
            const int cnt  = 1 << i;
            const int ub = ((u >> (2 * i - 1)) << (2 * i - 1)) | (u & (step - 1));
            float4 E[4];
#pragma unroll
            for (int c = 0; c < 4; c++) E[c] = make_float4(0.f, 0.f, 0.f, 0.f);
            float Dr = 0.f;
#pragma unroll
            for (int k = 0; k < cnt; k++) {
                const float4* Rp = (const float4*)(&Xs[(ub + k * step) * PAD_ + qoff]);
                const float4 R0 = Rp[0], R1 = Rp[1], R2 = Rp[2], R3 = Rp[3];
                const float e = __expf(qreduce(dot16(Q, R0, R1, R2, R3)) * 0.125f);
                Dr += e;
                E[0].x = fmaf(e, R0.x, E[0].x); E[0].y = fmaf(e, R0.y, E[0].y);
                E[0].z = fmaf(e, R0.z, E[0].z); E[0].w = fmaf(e, R0.w, E[0].w);
                E[1].x = fmaf(e, R1.x, E[1].x); E[1].y = fmaf(e, R1.y, E[1].y);
                E[1].z = fmaf(e, R1.z, E[1].z); E[1].w = fmaf(e, R1.w, E[1].w);
                E[2].x = fmaf(e, R2.x, E[2].x); E[2].y = fmaf(e, R2.y, E[2].y);
                E[2].z = fmaf(e, R2.z, E[2].z); E[2].w = fmaf(e, R2.w, E[2].w);
                E[3].x = fmaf(e, R3.x, E[3].x); E[3].y = fmaf(e, R3.y, E[3].y);
                E[3].z = fmaf(e, R3.z, E[3].z); E[3].w = fmaf(e, R3.w, E[3].w);
            }
            dn += Dr;
            const float r = 1.0f / Dr;
#pragma unroll
            for (int c = 0; c < 4; c++) {
                acc[c].x = fmaf(E[c].x, r, acc[c].x); acc[c].y = fmaf(E[c].y, r, acc[c].y);
                acc[c].z = fmaf(E[c].z, r, acc[c].z); acc[c].w = fmaf(E[c].w, r, acc[c].w);
            }
        }
    };
    rates123(Q0, u0, acc0, den0);
    rates123(Q1, u1, acc1, den1);

    // rates 4,5: (u0, u0+16) share the group -> read each key row once
#pragma unroll
    for (int i = 4; i <= 5; i++) {
        const int step = 1 << (i - 1);
        const int cnt  = 1 << i;
        const int ub = ((u0 >> (2 * i - 1)) << (2 * i - 1)) | (u0 & (step - 1));
        float4 E0[4], E1[4];
#pragma unroll
        for (int c = 0; c < 4; c++) {
            E0[c] = make_float4(0.f, 0.f, 0.f, 0.f);
            E1[c] = make_float4(0.f, 0.f, 0.f, 0.f);
        }
        float D0 = 0.f, D1 = 0.f;
#pragma unroll 4
        for (int k = 0; k < cnt; k++) {
            const float4* Rp = (const float4*)(&Xs[(ub + k * step) * PAD_ + qoff]);
            const float4 R0 = Rp[0], R1 = Rp[1], R2 = Rp[2], R3 = Rp[3];
            const float e0 = __expf(qreduce(dot16(Q0, R0, R1, R2, R3)) * 0.125f);
            const float e1 = __expf(qreduce(dot16(Q1, R0, R1, R2, R3)) * 0.125f);
            D0 += e0; D1 += e1;
            E0[0].x = fmaf(e0, R0.x, E0[0].x); E0[0].y = fmaf(e0, R0.y, E0[0].y);
            E0[0].z = fmaf(e0, R0.z, E0[0].z); E0[0].w = fmaf(e0, R0.w, E0[0].w);
            E0[1].x = fmaf(e0, R1.x, E0[1].x); E0[1].y = fmaf(e0, R1.y, E0[1].y);
            E0[1].z = fmaf(e0, R1.z, E0[1].z); E0[1].w = fmaf(e0, R1.w, E0[1].w);
            E0[2].x = fmaf(e0, R2.x, E0[2].x); E0[2].y = fmaf(e0, R2.y, E0[2].y);
            E0[2].z = fmaf(e0, R2.z, E0[2].z); E0[2].w = fmaf(e0, R2.w, E0[2].w);
            E0[3].x = fmaf(e0, R3.x, E0[3].x); E0[3].y = fmaf(e0, R3.y, E0[3].y);
            E0[3].z = fmaf(e0, R3.z, E0[3].z); E0[3].w = fmaf(e0, R3.w, E0[3].w);
            E1[0].x = fmaf(e1, R0.x, E1[0].x); E1[0].y = fmaf(e1, R0.y, E1[0].y);
            E1[0].z = fmaf(e1, R0.z, E1[0].z); E1[0].w = fmaf(e1, R0.w, E1[0].w);
            E1[1].x = fmaf(e1, R1.x, E1[1].x); E1[1].y = fmaf(e1, R1.y, E1[1].y);
            E1[1].z = fmaf(e1, R1.z, E1[1].z); E1[1].w = fmaf(e1, R1.w, E1[1].w);
            E1[2].x = fmaf(e1, R2.x, E1[2].x); E1[2].y = fmaf(e1, R2.y, E1[2].y);
            E1[2].z = fmaf(e1, R2.z, E1[2].z); E1[2].w = fmaf(e1, R2.w, E1[2].w);
            E1[3].x = fmaf(e1, R3.x, E1[3].x); E1[3].y = fmaf(e1, R3.y, E1[3].y);
            E1[3].z = fmaf(e1, R3.z, E1[3].z); E1[3].w = fmaf(e1, R3.w, E1[3].w);
        }
        den0 += D0; den1 += D1;
        const float r0 = 1.0f / D0, r1 = 1.0f / D1;
#pragma unroll
        for (int c = 0; c < 4; c++) {
            acc0[c].x = fmaf(E0[c].x, r0, acc0[c].x); acc0[c].y = fmaf(E0[c].y, r0, acc0[c].y);
            acc0[c].z = fmaf(E0[c].z, r0, acc0[c].z); acc0[c].w = fmaf(E0[c].w, r0, acc0[c].w);
            acc1[c].x = fmaf(E1[c].x, r1, acc1[c].x); acc1[c].y = fmaf(E1[c].y, r1, acc1[c].y);
            acc1[c].z = fmaf(E1[c].z, r1, acc1[c].z); acc1[c].w = fmaf(E1[c].w, r1, acc1[c].w);
        }
    }

    // write back
    {
        const int tA = t0 + 2 * u0 + p;
        float* opA = out + ((size_t)b * L_ + tA) * D_ + h * 64 + qoff;
#pragma unroll
        for (int c = 0; c < 4; c++) *(float4*)(opA + c * 4) = acc0[c];
        if (qt == 0) den[((size_t)b * L_ + tA) * H_ + h] = den0;

        const int tB = t0 + 2 * u1 + p;
        float* opB = out + ((size_t)b * L_ + tB) * D_ + h * 64 + qoff;
#pragma unroll
        for (int c = 0; c < 4; c++) *(float4*)(opB + c * 4) = acc1[c];
        if (qt == 0) den[((size_t)b * L_ + tB) * H_ + h] = den1;
    }
}

// K2: per token, w = softmax over heads of den; scale the 2048-wide row in place.
__global__ __launch_bounds__(256)
void ddattn_k2(float* __restrict__ out, const float* __restrict__ den) {
    const int tok = blockIdx.x;
    __shared__ float sden[H_];
    if (threadIdx.x < H_) sden[threadIdx.x] = den[(size_t)tok * H_ + threadIdx.x];
    __syncthreads();

    float mx = -3.4e38f;
#pragma unroll
    for (int hh = 0; hh < H_; hh++) mx = fmaxf(mx, sden[hh]);
    float sum = 0.f;
#pragma unroll
    for (int hh = 0; hh < H_; hh++) sum += __expf(sden[hh] - mx);
    const float inv = 1.0f / sum;

    float4* o4 = (float4*)(out + (size_t)tok * D_);
#pragma unroll
    for (int it = 0; it < 2; it++) {
        const int idx = it * 256 + threadIdx.x;
        const int hh  = idx >> 4;
        const float w = __expf(sden[hh] - mx) * inv;
        float4 vv = o4[idx];
        vv.x *= w; vv.y *= w; vv.z *= w; vv.w *= w;
        o4[idx] = vv;
    }
}

extern "C" void kernel_launch(void* const* d_in, const int* in_sizes, int n_in,
                              void* d_out, int out_size, void* d_ws, size_t ws_size,
                              hipStream_t stream) {
    const float* x = (const float*)d_in[0];
    float* out = (float*)d_out;
    float* den = (float*)d_ws;  // B*L*H fp32 = 4 MB scratch

    ddattn_k1<<<dim3(B_ * (L_ / WIN_) * 2 * H_ * 2), dim3(512), 0, stream>>>(x, out, den);
    ddattn_k2<<<dim3(B_ * L_), dim3(256), 0, stream>>>(out, den);
}

// Round 3
// 1079.223 us; speedup vs baseline: 3.9119x; 1.5313x over previous
//
#include <hip/hip_runtime.h>

#define B_   4
#define L_   8192
#define D_   2048
#define H_   32
#define WIN_ 1024
#define U_   512      // tokens per (window, parity) slice
#define PAD_ 68       // 64 + 4 pad

// cross-lane add via DPP on the VALU pipe (NOT ds_swizzle / DS pipe)
template <int CTRL>
__device__ __forceinline__ float dpp_add(float v) {
    int s = __builtin_amdgcn_update_dpp(0, __builtin_bit_cast(int, v), CTRL, 0xf, 0xf, true);
    return v + __builtin_bit_cast(float, s);
}
// sum over the 8-lane group (lanes 8g..8g+7): xor1, xor2 (quad_perm), xor4 (row_half_mirror)
__device__ __forceinline__ float sum8(float v) {
    v = dpp_add<0xB1>(v);    // quad_perm [1,0,3,2]
    v = dpp_add<0x4E>(v);    // quad_perm [2,3,0,1]
    v = dpp_add<0x141>(v);   // row_half_mirror
    return v;
}

__device__ __forceinline__ float dot8(const float4& A0, const float4& A1,
                                      const float4& R0, const float4& R1) {
    float a = 0.f, b = 0.f;
    a = fmaf(A0.x, R0.x, a); b = fmaf(A0.y, R0.y, b);
    a = fmaf(A0.z, R0.z, a); b = fmaf(A0.w, R0.w, b);
    a = fmaf(A1.x, R1.x, a); b = fmaf(A1.y, R1.y, b);
    a = fmaf(A1.z, R1.z, a); b = fmaf(A1.w, R1.w, b);
    return a + b;
}

__device__ __forceinline__ void fma4(float4& a, float s, const float4& b) {
    a.x = fmaf(s, b.x, a.x); a.y = fmaf(s, b.y, a.y);
    a.z = fmaf(s, b.z, a.z); a.w = fmaf(s, b.w, a.w);
}

// K1: one block per (b, win, parity, head, query-half). 1024 threads =
// 128 query-pairs (u, u+16) x 8 head-dim octants (8 dims each). The +16 pair
// shares its rate-3/4/5 groups (56 of 62 keys) -> those LDS rows are read once
// for two queries. Per-thread live state ~75 VGPRs -> no scratch spills.
__global__ __launch_bounds__(1024, 4)
void ddattn_k1(const float* __restrict__ x, float* __restrict__ out,
               float* __restrict__ den) {
    const int bid = blockIdx.x;
    const int qhf = bid & 1;
    const int h   = (bid >> 1) & 31;
    const int p   = (bid >> 6) & 1;
    const int win = (bid >> 7) & 7;
    const int b   = bid >> 10;

    __shared__ float Xs[U_ * PAD_];
    const int t0 = win * WIN_;
    const float* xb = x + ((size_t)b * L_ + (size_t)(t0 + p)) * D_ + h * 64;

    for (int idx = threadIdx.x; idx < U_ * 16; idx += 1024) {
        const int row = idx >> 4, c = idx & 15;
        *(float4*)(&Xs[row * PAD_ + c * 4]) =
            *(const float4*)(xb + (size_t)row * (2 * D_) + c * 4);
    }
    __syncthreads();

    const int oct = threadIdx.x & 7;     // head-dim octant (8 dims)
    const int j   = threadIdx.x >> 3;    // pair slot 0..127
    const int u0  = (j & 15) | ((j >> 4) << 5) | (qhf << 8);   // bit4 = 0
    const int u1  = u0 + 16;                                   // bit4 = 1
    const int off = oct * 8;

    float4 Q00 = *(const float4*)(&Xs[u0 * PAD_ + off]);
    float4 Q01 = *(const float4*)(&Xs[u0 * PAD_ + off + 4]);
    float4 Q10 = *(const float4*)(&Xs[u1 * PAD_ + off]);
    float4 Q11 = *(const float4*)(&Xs[u1 * PAD_ + off + 4]);

    // rate 0: probs == 1 -> out += x ; den = exp(|x|^2 / 8)
    float4 acc00 = Q00, acc01 = Q01, acc10 = Q10, acc11 = Q11;
    float den0 = __expf(sum8(dot8(Q00, Q01, Q00, Q01)) * 0.125f);
    float den1 = __expf(sum8(dot8(Q10, Q11, Q10, Q11)) * 0.125f);

    // rates 1,2: pair members have different groups -> per query
    auto rate_single = [&](const float4& A0, const float4& A1, int u,
                           float4& c0, float4& c1, float& dn, int i) {
        const int step = 1 << (i - 1), cnt = 1 << i;
        const int ub = ((u >> (2 * i - 1)) << (2 * i - 1)) | (u & (step - 1));
        float4 E0 = make_float4(0, 0, 0, 0), E1 = make_float4(0, 0, 0, 0);
        float Dr = 0.f;
        for (int k = 0; k < cnt; k++) {
            const float4* Rp = (const float4*)(&Xs[(ub + k * step) * PAD_ + off]);
            const float4 R0 = Rp[0], R1 = Rp[1];
            const float e = __expf(sum8(dot8(A0, A1, R0, R1)) * 0.125f);
            Dr += e;
            fma4(E0, e, R0); fma4(E1, e, R1);
        }
        dn += Dr;
        const float r = 1.0f / Dr;
        fma4(c0, r, E0); fma4(c1, r, E1);
    };
    rate_single(Q00, Q01, u0, acc00, acc01, den0, 1);
    rate_single(Q00, Q01, u0, acc00, acc01, den0, 2);
    rate_single(Q10, Q11, u1, acc10, acc11, den1, 1);
    rate_single(Q10, Q11, u1, acc10, acc11, den1, 2);

    // rates 3,4,5: (u0, u0+16) share the group (bit4 in the free range) ->
    // each key row read from LDS once, used by both queries
#pragma unroll
    for (int i = 3; i <= 5; i++) {
        const int step = 1 << (i - 1), cnt = 1 << i;
        const int ub = ((u0 >> (2 * i - 1)) << (2 * i - 1)) | (u0 & (step - 1));
        float4 E00 = make_float4(0, 0, 0, 0), E01 = make_float4(0, 0, 0, 0);
        float4 E10 = make_float4(0, 0, 0, 0), E11 = make_float4(0, 0, 0, 0);
        float D0 = 0.f, D1 = 0.f;
#pragma unroll 4
        for (int k = 0; k < cnt; k++) {
            const float4* Rp = (const float4*)(&Xs[(ub + k * step) * PAD_ + off]);
            const float4 R0 = Rp[0], R1 = Rp[1];
            const float d0 = sum8(dot8(Q00, Q01, R0, R1));
            const float d1 = sum8(dot8(Q10, Q11, R0, R1));
            const float e0 = __expf(d0 * 0.125f);
            const float e1 = __expf(d1 * 0.125f);
            D0 += e0; D1 += e1;
            fma4(E00, e0, R0); fma4(E01, e0, R1);
            fma4(E10, e1, R0); fma4(E11, e1, R1);
        }
        den0 += D0; den1 += D1;
        const float r0 = 1.0f / D0, r1 = 1.0f / D1;
        fma4(acc00, r0, E00); fma4(acc01, r0, E01);
        fma4(acc10, r1, E10); fma4(acc11, r1, E11);
    }

    // write back (per j-group: 8 octs x 32B contiguous -> coalesced)
    {
        const int tA = t0 + 2 * u0 + p;
        float* opA = out + ((size_t)b * L_ + tA) * D_ + h * 64 + off;
        *(float4*)opA = acc00; *(float4*)(opA + 4) = acc01;
        if (oct == 0) den[((size_t)b * L_ + tA) * H_ + h] = den0;

        const int tB = t0 + 2 * u1 + p;
        float* opB = out + ((size_t)b * L_ + tB) * D_ + h * 64 + off;
        *(float4*)opB = acc10; *(float4*)(opB + 4) = acc11;
        if (oct == 0) den[((size_t)b * L_ + tB) * H_ + h] = den1;
    }
}

// K2: per token, w = softmax over heads of den; scale the 2048-wide row.
// 4 tokens per 512-thread block.
__global__ __launch_bounds__(512)
void ddattn_k2(float* __restrict__ out, const float* __restrict__ den) {
    const int tok0 = blockIdx.x * 4;
    __shared__ float sden[4][H_];
    if (threadIdx.x < 128)
        sden[threadIdx.x >> 5][threadIdx.x & 31] = den[(size_t)tok0 * H_ + threadIdx.x];
    __syncthreads();

    const int tt = threadIdx.x >> 7;    // token 0..3
    const int q  = threadIdx.x & 127;   // 128 threads per token
    float mx = -3.4e38f;
#pragma unroll
    for (int hh = 0; hh < H_; hh++) mx = fmaxf(mx, sden[tt][hh]);
    float sum = 0.f;
#pragma unroll
    for (int hh = 0; hh < H_; hh++) sum += __expf(sden[tt][hh] - mx);
    const float inv = 1.0f / sum;

    float4* o4 = (float4*)(out + (size_t)(tok0 + tt) * D_);
#pragma unroll
    for (int c = 0; c < 4; c++) {
        const int idx = q + 128 * c;               // 512 float4 per token
        const float w = __expf(sden[tt][idx >> 4] - mx) * inv;
        float4 vv = o4[idx];
        vv.x *= w; vv.y *= w; vv.z *= w; vv.w *= w;
        o4[idx] = vv;
    }
}

extern "C" void kernel_launch(void* const* d_in, const int* in_sizes, int n_in,
                              void* d_out, int out_size, void* d_ws, size_t ws_size,
                              hipStream_t stream) {
    const float* x = (const float*)d_in[0];
    float* out = (float*)d_out;
    float* den = (float*)d_ws;  // B*L*H fp32 = 4 MB scratch

    ddattn_k1<<<dim3(B_ * (L_ / WIN_) * 2 * H_ * 2), dim3(1024), 0, stream>>>(x, out, den);
    ddattn_k2<<<dim3(B_ * L_ / 4), dim3(512), 0, stream>>>(out, den);
}

// Round 4
// 1031.761 us; speedup vs baseline: 4.0918x; 1.0460x over previous
//
#include <hip/hip_runtime.h>

#define B_   4
#define L_   8192
#define D_   2048
#define H_   32
#define WIN_ 1024
#define U_   512      // tokens per (window, parity) slice
#define PAD_ 68       // 64 + 4 pad

// cross-lane add via DPP on the VALU pipe (NOT ds_swizzle / DS pipe)
template <int CTRL>
__device__ __forceinline__ float dpp_add(float v) {
    int s = __builtin_amdgcn_update_dpp(0, __builtin_bit_cast(int, v), CTRL, 0xf, 0xf, true);
    return v + __builtin_bit_cast(float, s);
}
// sum over the 8-lane group: xor1, xor2 (quad_perm), xor4 (row_half_mirror)
__device__ __forceinline__ float sum8(float v) {
    v = dpp_add<0xB1>(v);    // quad_perm [1,0,3,2]
    v = dpp_add<0x4E>(v);    // quad_perm [2,3,0,1]
    v = dpp_add<0x141>(v);   // row_half_mirror
    return v;
}

__device__ __forceinline__ float dot8(const float4& A0, const float4& A1,
                                      const float4& R0, const float4& R1) {
    float a = 0.f, b = 0.f;
    a = fmaf(A0.x, R0.x, a); b = fmaf(A0.y, R0.y, b);
    a = fmaf(A0.z, R0.z, a); b = fmaf(A0.w, R0.w, b);
    a = fmaf(A1.x, R1.x, a); b = fmaf(A1.y, R1.y, b);
    a = fmaf(A1.z, R1.z, a); b = fmaf(A1.w, R1.w, b);
    return a + b;
}

__device__ __forceinline__ void fma4(float4& a, float s, const float4& b) {
    a.x = fmaf(s, b.x, a.x); a.y = fmaf(s, b.y, a.y);
    a.z = fmaf(s, b.z, a.z); a.w = fmaf(s, b.w, a.w);
}

// K1: one block per (b, win, parity, head). 1024 threads = 128 pair-slots x
// 8 head-dim octants; an in-block loop over qhf covers all 256 query pairs
// against ONE LDS staging of the 512-row parity slice. The (u,u+16) pair
// shares its rate-3/4/5 groups (56 of 62 keys). waves_per_eu(4,4) pins the
// RA budget at 128 VGPRs (LDS already caps the CU at 1 block = 4 waves/EU,
// so chasing 8 waves/EU = 64 VGPRs only buys spills -- the R3 failure mode).
__global__
__attribute__((amdgpu_flat_work_group_size(1024, 1024), amdgpu_waves_per_eu(4, 4)))
void ddattn_k1(const float* __restrict__ x, float* __restrict__ out,
               float* __restrict__ den) {
    const int bid = blockIdx.x;
    const int h   = bid & 31;
    const int p   = (bid >> 5) & 1;
    const int win = (bid >> 6) & 7;
    const int b   = bid >> 9;

    __shared__ float Xs[U_ * PAD_];
    const int t0 = win * WIN_;
    const float* xb = x + ((size_t)b * L_ + (size_t)(t0 + p)) * D_ + h * 64;

    for (int idx = threadIdx.x; idx < U_ * 16; idx += 1024) {
        const int row = idx >> 4, c = idx & 15;
        *(float4*)(&Xs[row * PAD_ + c * 4]) =
            *(const float4*)(xb + (size_t)row * (2 * D_) + c * 4);
    }
    __syncthreads();

    const int oct = threadIdx.x & 7;     // head-dim octant (8 dims)
    const int j   = threadIdx.x >> 3;    // pair slot 0..127
    const int off = oct * 8;

#pragma unroll 1
    for (int qhf = 0; qhf < 2; qhf++) {
        const int u0 = (j & 15) | ((j >> 4) << 5) | (qhf << 8);   // bit4 = 0
        const int u1 = u0 + 16;                                   // bit4 = 1

        float4 Q00 = *(const float4*)(&Xs[u0 * PAD_ + off]);
        float4 Q01 = *(const float4*)(&Xs[u0 * PAD_ + off + 4]);
        float4 Q10 = *(const float4*)(&Xs[u1 * PAD_ + off]);
        float4 Q11 = *(const float4*)(&Xs[u1 * PAD_ + off + 4]);

        // rate 0: probs == 1 -> out += x ; den = exp(|x|^2 / 8)
        float4 acc00 = Q00, acc01 = Q01, acc10 = Q10, acc11 = Q11;
        float den0 = __expf(sum8(dot8(Q00, Q01, Q00, Q01)) * 0.125f);
        float den1 = __expf(sum8(dot8(Q10, Q11, Q10, Q11)) * 0.125f);

        // rates 1,2: pair members have different groups -> per query
        auto rate_single = [&](const float4& A0, const float4& A1, int u,
                               float4& c0, float4& c1, float& dn, int i) {
            const int step = 1 << (i - 1), cnt = 1 << i;
            const int ub = ((u >> (2 * i - 1)) << (2 * i - 1)) | (u & (step - 1));
            float4 E0 = make_float4(0, 0, 0, 0), E1 = make_float4(0, 0, 0, 0);
            float Dr = 0.f;
            for (int k = 0; k < cnt; k++) {
                const float4* Rp = (const float4*)(&Xs[(ub + k * step) * PAD_ + off]);
                const float4 R0 = Rp[0], R1 = Rp[1];
                const float e = __expf(sum8(dot8(A0, A1, R0, R1)) * 0.125f);
                Dr += e;
                fma4(E0, e, R0); fma4(E1, e, R1);
            }
            dn += Dr;
            const float r = 1.0f / Dr;
            fma4(c0, r, E0); fma4(c1, r, E1);
        };
        rate_single(Q00, Q01, u0, acc00, acc01, den0, 1);
        rate_single(Q00, Q01, u0, acc00, acc01, den0, 2);
        rate_single(Q10, Q11, u1, acc10, acc11, den1, 1);
        rate_single(Q10, Q11, u1, acc10, acc11, den1, 2);

        // rates 3,4,5: the pair shares the group -> each key row read once
#pragma unroll
        for (int i = 3; i <= 5; i++) {
            const int step = 1 << (i - 1), cnt = 1 << i;
            const int ub = ((u0 >> (2 * i - 1)) << (2 * i - 1)) | (u0 & (step - 1));
            float4 E00 = make_float4(0, 0, 0, 0), E01 = make_float4(0, 0, 0, 0);
            float4 E10 = make_float4(0, 0, 0, 0), E11 = make_float4(0, 0, 0, 0);
            float D0 = 0.f, D1 = 0.f;
#pragma unroll 4
            for (int k = 0; k < cnt; k++) {
                const float4* Rp = (const float4*)(&Xs[(ub + k * step) * PAD_ + off]);
                const float4 R0 = Rp[0], R1 = Rp[1];
                const float d0 = sum8(dot8(Q00, Q01, R0, R1));
                const float d1 = sum8(dot8(Q10, Q11, R0, R1));
                const float e0 = __expf(d0 * 0.125f);
                const float e1 = __expf(d1 * 0.125f);
                D0 += e0; D1 += e1;
                fma4(E00, e0, R0); fma4(E01, e0, R1);
                fma4(E10, e1, R0); fma4(E11, e1, R1);
            }
            den0 += D0; den1 += D1;
            const float r0 = 1.0f / D0, r1 = 1.0f / D1;
            fma4(acc00, r0, E00); fma4(acc01, r0, E01);
            fma4(acc10, r1, E10); fma4(acc11, r1, E11);
        }

        // write back (8 octs x 32B contiguous per token -> coalesced)
        const int tA = t0 + 2 * u0 + p;
        float* opA = out + ((size_t)b * L_ + tA) * D_ + h * 64 + off;
        *(float4*)opA = acc00; *(float4*)(opA + 4) = acc01;
        if (oct == 0) den[((size_t)b * L_ + tA) * H_ + h] = den0;

        const int tB = t0 + 2 * u1 + p;
        float* opB = out + ((size_t)b * L_ + tB) * D_ + h * 64 + off;
        *(float4*)opB = acc10; *(float4*)(opB + 4) = acc11;
        if (oct == 0) den[((size_t)b * L_ + tB) * H_ + h] = den1;
    }
}

// K2: per token, w = softmax over heads of den; scale the 2048-wide row.
// 2 tokens per 256-thread block; weights computed ONCE into LDS, then a pure
// streaming multiply.
__global__ __launch_bounds__(256)
void ddattn_k2(float* __restrict__ out, const float* __restrict__ den) {
    const int tok0 = blockIdx.x * 2;
    __shared__ float sden[2][H_];
    __shared__ float w2[2][H_];
    if (threadIdx.x < 64)
        sden[threadIdx.x >> 5][threadIdx.x & 31] = den[(size_t)tok0 * H_ + threadIdx.x];
    __syncthreads();
    if (threadIdx.x < 64) {
        const int tt = threadIdx.x >> 5, hh = threadIdx.x & 31;
        float mx = -3.4e38f;
#pragma unroll
        for (int k = 0; k < H_; k++) mx = fmaxf(mx, sden[tt][k]);
        float s = 0.f;
#pragma unroll
        for (int k = 0; k < H_; k++) s += __expf(sden[tt][k] - mx);
        w2[tt][hh] = __expf(sden[tt][hh] - mx) / s;
    }
    __syncthreads();

    float4* o4 = (float4*)(out + (size_t)tok0 * D_);
#pragma unroll
    for (int c = 0; c < 4; c++) {
        const int idx = threadIdx.x + 256 * c;        // 1024 float4 = 2 tokens
        const float w = w2[idx >> 9][(idx >> 4) & 31];
        float4 vv = o4[idx];
        vv.x *= w; vv.y *= w; vv.z *= w; vv.w *= w;
        o4[idx] = vv;
    }
}

extern "C" void kernel_launch(void* const* d_in, const int* in_sizes, int n_in,
                              void* d_out, int out_size, void* d_ws, size_t ws_size,
                              hipStream_t stream) {
    const float* x = (const float*)d_in[0];
    float* out = (float*)d_out;
    float* den = (float*)d_ws;  // B*L*H fp32 = 4 MB scratch

    ddattn_k1<<<dim3(B_ * (L_ / WIN_) * 2 * H_), dim3(1024), 0, stream>>>(x, out, den);
    ddattn_k2<<<dim3(B_ * L_ / 2), dim3(256), 0, stream>>>(out, den);
}

// Round 5
// 965.909 us; speedup vs baseline: 4.3708x; 1.0682x over previous
//
#include <hip/hip_runtime.h>

#define B_   4
#define L_   8192
#define D_   2048
#define H_   32
#define WIN_ 1024
#define U_   512      // tokens per (window, parity) slice
#define PAD_ 68       // 64 + 4 pad

// cross-lane add via DPP on the VALU pipe (NOT ds_swizzle / DS pipe)
template <int CTRL>
__device__ __forceinline__ float dpp_add(float v) {
    int s = __builtin_amdgcn_update_dpp(0, __builtin_bit_cast(int, v), CTRL, 0xf, 0xf, true);
    return v + __builtin_bit_cast(float, s);
}
// sum over an aligned 16-lane row. After xor1/xor2 each quad is uniform, so
// half-mirror acts as xor4 and row-mirror as xor8.
__device__ __forceinline__ float sum16(float v) {
    v = dpp_add<0xB1>(v);    // quad_perm [1,0,3,2]  (xor 1)
    v = dpp_add<0x4E>(v);    // quad_perm [2,3,0,1]  (xor 2)
    v = dpp_add<0x141>(v);   // row_half_mirror      (xor 4 after uniformity)
    v = dpp_add<0x140>(v);   // row_mirror           (xor 8 after uniformity)
    return v;
}

__device__ __forceinline__ float dot4(const float4& A, const float4& R) {
    float a = 0.f, b = 0.f;
    a = fmaf(A.x, R.x, a); b = fmaf(A.y, R.y, b);
    a = fmaf(A.z, R.z, a); b = fmaf(A.w, R.w, b);
    return a + b;
}

__device__ __forceinline__ void fma4(float4& a, float s, const float4& b) {
    a.x = fmaf(s, b.x, a.x); a.y = fmaf(s, b.y, a.y);
    a.z = fmaf(s, b.z, a.z); a.w = fmaf(s, b.w, a.w);
}

// K1: one block per (b, win, parity, head). 1024 threads = 64 pair-slots x
// 16 lanes (4 head-dims each); 4 in-block iterations cover all 256 query
// pairs against ONE LDS staging of the 512-row parity slice. The (u, u+16)
// pair shares its rate-3/4/5 key groups (56 of 68 row visits serve both
// queries). 4 dims/lane keeps live state ~40 VGPRs: fits the 64-VGPR budget
// the RA insists on (R3/R4 showed attributes can't raise it), so zero
// scratch spills.
__global__ __launch_bounds__(1024)
void ddattn_k1(const float* __restrict__ x, float* __restrict__ out,
               float* __restrict__ den) {
    const int bid = blockIdx.x;
    const int h   = bid & 31;
    const int p   = (bid >> 5) & 1;
    const int win = (bid >> 6) & 7;
    const int b   = bid >> 9;

    __shared__ float Xs[U_ * PAD_];
    const int t0 = win * WIN_;
    const float* xb = x + ((size_t)b * L_ + (size_t)(t0 + p)) * D_ + h * 64;

    for (int idx = threadIdx.x; idx < U_ * 16; idx += 1024) {
        const int row = idx >> 4, c = idx & 15;
        *(float4*)(&Xs[row * PAD_ + c * 4]) =
            *(const float4*)(xb + (size_t)row * (2 * D_) + c * 4);
    }
    __syncthreads();

    const int lane16 = threadIdx.x & 15;   // 4-dim slice within the head
    const int j      = threadIdx.x >> 4;   // pair slot 0..63
    const int off    = lane16 * 4;

#pragma unroll 1
    for (int qq = 0; qq < 4; qq++) {
        const int P  = qq * 64 + j;                      // pair index 0..255
        const int u0 = (P & 15) | ((P >> 4) << 5);       // bit4 = 0
        const int u1 = u0 + 16;                          // bit4 = 1

        float4 Q0 = *(const float4*)(&Xs[u0 * PAD_ + off]);
        float4 Q1 = *(const float4*)(&Xs[u1 * PAD_ + off]);

        // rate 0: probs == 1 -> out += x ; den = exp(|x|^2 / 8)
        float4 acc0 = Q0, acc1 = Q1;
        float den0 = __expf(sum16(dot4(Q0, Q0)) * 0.125f);
        float den1 = __expf(sum16(dot4(Q1, Q1)) * 0.125f);

        // rates 1,2: pair members have different groups -> per query
        auto rate_single = [&](const float4& Q, int u, float4& acc, float& dn, int i) {
            const int step = 1 << (i - 1), cnt = 1 << i;
            const int ub = ((u >> (2 * i - 1)) << (2 * i - 1)) | (u & (step - 1));
            float4 E = make_float4(0, 0, 0, 0);
            float Dr = 0.f;
            for (int k = 0; k < cnt; k++) {
                const float4 R = *(const float4*)(&Xs[(ub + k * step) * PAD_ + off]);
                const float e = __expf(sum16(dot4(Q, R)) * 0.125f);
                Dr += e;
                fma4(E, e, R);
            }
            dn += Dr;
            fma4(acc, 1.0f / Dr, E);
        };
        rate_single(Q0, u0, acc0, den0, 1);
        rate_single(Q0, u0, acc0, den0, 2);
        rate_single(Q1, u1, acc1, den1, 1);
        rate_single(Q1, u1, acc1, den1, 2);

        // rates 3,4,5: the pair shares the group -> each key row read once
#pragma unroll
        for (int i = 3; i <= 5; i++) {
            const int step = 1 << (i - 1), cnt = 1 << i;
            const int ub = ((u0 >> (2 * i - 1)) << (2 * i - 1)) | (u0 & (step - 1));
            float4 E0 = make_float4(0, 0, 0, 0), E1 = make_float4(0, 0, 0, 0);
            float D0 = 0.f, D1 = 0.f;
#pragma unroll 4
            for (int k = 0; k < cnt; k++) {
                const float4 R = *(const float4*)(&Xs[(ub + k * step) * PAD_ + off]);
                const float e0 = __expf(sum16(dot4(Q0, R)) * 0.125f);
                const float e1 = __expf(sum16(dot4(Q1, R)) * 0.125f);
                D0 += e0; D1 += e1;
                fma4(E0, e0, R); fma4(E1, e1, R);
            }
            den0 += D0; den1 += D1;
            fma4(acc0, 1.0f / D0, E0);
            fma4(acc1, 1.0f / D1, E1);
        }

        // write back (16 lanes x 16B contiguous per token -> coalesced 256B)
        const int tA = t0 + 2 * u0 + p;
        float* opA = out + ((size_t)b * L_ + tA) * D_ + h * 64 + off;
        *(float4*)opA = acc0;
        if (lane16 == 0) den[((size_t)b * L_ + tA) * H_ + h] = den0;

        const int tB = t0 + 2 * u1 + p;
        float* opB = out + ((size_t)b * L_ + tB) * D_ + h * 64 + off;
        *(float4*)opB = acc1;
        if (lane16 == 0) den[((size_t)b * L_ + tB) * H_ + h] = den1;
    }
}

// K2: per token, w = softmax over heads of den; scale the 2048-wide row.
// 2 tokens per 256-thread block; weights computed once into LDS, then a pure
// streaming multiply.
__global__ __launch_bounds__(256)
void ddattn_k2(float* __restrict__ out, const float* __restrict__ den) {
    const int tok0 = blockIdx.x * 2;
    __shared__ float sden[2][H_];
    __shared__ float w2[2][H_];
    if (threadIdx.x < 64)
        sden[threadIdx.x >> 5][threadIdx.x & 31] = den[(size_t)tok0 * H_ + threadIdx.x];
    __syncthreads();
    if (threadIdx.x < 64) {
        const int tt = threadIdx.x >> 5, hh = threadIdx.x & 31;
        float mx = -3.4e38f;
#pragma unroll
        for (int k = 0; k < H_; k++) mx = fmaxf(mx, sden[tt][k]);
        float s = 0.f;
#pragma unroll
        for (int k = 0; k < H_; k++) s += __expf(sden[tt][k] - mx);
        w2[tt][hh] = __expf(sden[tt][hh] - mx) / s;
    }
    __syncthreads();

    float4* o4 = (float4*)(out + (size_t)tok0 * D_);
#pragma unroll
    for (int c = 0; c < 4; c++) {
        const int idx = threadIdx.x + 256 * c;        // 1024 float4 = 2 tokens
        const float w = w2[idx >> 9][(idx >> 4) & 31];
        float4 vv = o4[idx];
        vv.x *= w; vv.y *= w; vv.z *= w; vv.w *= w;
        o4[idx] = vv;
    }
}

extern "C" void kernel_launch(void* const* d_in, const int* in_sizes, int n_in,
                              void* d_out, int out_size, void* d_ws, size_t ws_size,
                              hipStream_t stream) {
    const float* x = (const float*)d_in[0];
    float* out = (float*)d_out;
    float* den = (float*)d_ws;  // B*L*H fp32 = 4 MB scratch

    ddattn_k1<<<dim3(B_ * (L_ / WIN_) * 2 * H_), dim3(1024), 0, stream>>>(x, out, den);
    ddattn_k2<<<dim3(B_ * L_ / 2), dim3(256), 0, stream>>>(out, den);
}